// Round 8
// baseline (365.862 us; speedup 1.0000x reference)
//
#include <hip/hip_runtime.h>
#include <hip/hip_bf16.h>
#include <stdint.h>

typedef unsigned int u32;
typedef unsigned short u16;
typedef __attribute__((ext_vector_type(8))) short short8;   // 8 bf16 = 4 VGPRs (MFMA A/B frag)
typedef __attribute__((ext_vector_type(4))) float f32x4;    // MFMA C/D frag

#define CSRB 256    // blocks in the fused CSR-build kernel (<= 256 CUs -> co-resident)

__device__ __forceinline__ float bf2f(u16 u) {
    union { u32 u; float f; } v; v.u = ((u32)u) << 16; return v.f;
}
__device__ __forceinline__ u16 f2bf(float f) {
    u32 u = __float_as_uint(f);
    u32 r = (u + 0x7FFFu + ((u >> 16) & 1u)) >> 16;  // RNE
    return (u16)r;
}
__device__ __forceinline__ u32 packbf(float lo, float hi) {
    return ((u32)f2bf(hi) << 16) | (u32)f2bf(lo);
}

// Grid-wide barrier for a co-resident grid (generation counter, agent scope).
// cnt/gen must be zeroed by a PRIOR kernel.
__device__ __forceinline__ void grid_bar(int* cnt, int* gen, int nb) {
    __syncthreads();
    if (threadIdx.x == 0) {
        __threadfence();   // release: drain stores, writeback L2 (agent scope)
        int g = __hip_atomic_load(gen, __ATOMIC_RELAXED, __HIP_MEMORY_SCOPE_AGENT);
        int prev = __hip_atomic_fetch_add(cnt, 1, __ATOMIC_ACQ_REL, __HIP_MEMORY_SCOPE_AGENT);
        if (prev == nb - 1) {
            __hip_atomic_store(cnt, 0, __ATOMIC_RELAXED, __HIP_MEMORY_SCOPE_AGENT);
            __hip_atomic_store(gen, g + 1, __ATOMIC_RELEASE, __HIP_MEMORY_SCOPE_AGENT);
        } else {
            while (__hip_atomic_load(gen, __ATOMIC_ACQUIRE, __HIP_MEMORY_SCOPE_AGENT) <= g)
                __builtin_amdgcn_s_sleep(1);
        }
    }
    __syncthreads();
}

// Block 0: flags[0]=1 if float tensors are f32 (else bf16), flags[1]=1 if
// edge_index int64 (else int32); zero barrier words. ALL blocks: zero deg.
__global__ __launch_bounds__(256) void detect_zero_k(const u32* __restrict__ xw,
                                                     const u32* __restrict__ ew,
                                                     int* __restrict__ flags,
                                                     int* __restrict__ deg, int M) {
    const int t = threadIdx.x;
    const int i4 = (blockIdx.x * 256 + t) * 4;
    if (i4 + 4 <= M) *(int4*)(deg + i4) = make_int4(0, 0, 0, 0);
    else { for (int j = 0; j < 4; j++) if (i4 + j < M) deg[i4 + j] = 0; }

    if (blockIdx.x == 0) {
        __shared__ int cnt;
        __shared__ u32 orr;
        if (t == 0) { cnt = 0; orr = 0u; }
        __syncthreads();
        int hits = 0;
        for (int i = t; i < 1024; i += 256) {
            u32 f = (xw[i] >> 7) & 0xFFu;
            if (f >= 100u && f <= 140u) hits++;
        }
        atomicAdd(&cnt, hits);
        atomicOr(&orr, ew[2 * t + 1]);
        __syncthreads();
        if (t == 0) {
            flags[0] = (cnt < 512) ? 1 : 0;
            flags[1] = (orr == 0u) ? 1 : 0;
            flags[8] = 0;   // barrier cnt
            flags[9] = 0;   // barrier gen
        }
    }
}

// Pre-pack W into B-frag order: chunk p = kb*N+n holds 8 bf16 of col n,
// rows k = kb*8..+7.
template<int N>
__device__ __forceinline__ void wpack_one(const void* W, uint4* wpk, int p, int f32w) {
    const int n = p & (N - 1);
    const int kb = p >> ((N == 128) ? 7 : 6);
    u32 pk[4];
    if (f32w) {
        const float* wp = (const float*)W + (size_t)(kb * 8) * N + n;
        #pragma unroll
        for (int jj = 0; jj < 4; jj++)
            pk[jj] = packbf(wp[(2 * jj) * N], wp[(2 * jj + 1) * N]);
    } else {
        const u16* wp = (const u16*)W + (size_t)(kb * 8) * N + n;
        #pragma unroll
        for (int jj = 0; jj < 4; jj++)
            pk[jj] = ((u32)wp[(2 * jj + 1) * N] << 16) | (u32)wp[(2 * jj) * N];
    }
    uint4 v; v.x = pk[0]; v.y = pk[1]; v.z = pk[2]; v.w = pk[3];
    wpk[p] = v;
}

// ===== fused CSR build: [wpack + count] | [tile sums] | [scan256] | [final] | [fill]
__global__ __launch_bounds__(256) void csr_build_k(
    const void* __restrict__ ei, int E, int M,
    int* __restrict__ flags,
    const void* __restrict__ W1, const void* __restrict__ W2,
    uint4* __restrict__ wpk1, uint4* __restrict__ wpk2,
    int* __restrict__ deg, int* __restrict__ bsum,
    int* __restrict__ off, int* __restrict__ cursor,
    float* __restrict__ dinv, int* __restrict__ eidx)
{
    const int bid = blockIdx.x, t = threadIdx.x;
    const int gtid = bid * 256 + t;
    const int GT = CSRB * 256;
    const int f32w = flags[0], i64 = flags[1];
    int* cnt = &flags[8];
    int* gen = &flags[9];

    // ---- phase A: wpack (blocks 0..11) + degree count ----
    if (bid < 8)       wpack_one<128>(W1, wpk1, bid * 256 + t, f32w);
    else if (bid < 12) wpack_one<64> (W2, wpk2, (bid - 8) * 256 + t, f32w);

    if (i64) {
        const long long* dp = (const long long*)ei + E;
        for (int i = gtid; i < E; i += GT) atomicAdd(&deg[(int)dp[i]], 1);
    } else {
        const int* dp = (const int*)ei + E;
        for (int i = gtid; i < E; i += GT) atomicAdd(&deg[dp[i]], 1);
    }
    grid_bar(cnt, gen, CSRB);

    // ---- phase B1: per-block tile sum (tile = 2 elems/thread) ----
    const int tile = (M + CSRB - 1) / CSRB;            // 391 for M=100000
    const int lo = bid * tile;
    const int idx0 = lo + 2 * t, idx1 = idx0 + 1;
    const bool in0 = (2 * t < tile)     && (idx0 < M);
    const bool in1 = (2 * t + 1 < tile) && (idx1 < M);
    {
        int s = (in0 ? deg[idx0] : 0) + (in1 ? deg[idx1] : 0);
        __shared__ int red[256];
        red[t] = s;
        __syncthreads();
        for (int d2 = 128; d2 > 0; d2 >>= 1) {
            if (t < d2) red[t] += red[t + d2];
            __syncthreads();
        }
        if (t == 0) bsum[bid] = red[0];
    }
    grid_bar(cnt, gen, CSRB);

    // ---- phase B2: block 0 exclusive-scans the 256 block sums ----
    if (bid == 0) {
        __shared__ int buf[2][256];
        int v = bsum[t];
        const int own = v;
        buf[0][t] = v;
        __syncthreads();
        int cur = 0;
        for (int d2 = 1; d2 < 256; d2 <<= 1) {
            int x = buf[cur][t];
            if (t >= d2) x += buf[cur][t - d2];
            buf[cur ^ 1][t] = x;
            __syncthreads();
            cur ^= 1;
        }
        bsum[t] = buf[cur][t] - own;                   // exclusive
        if (t == 255) off[M] = buf[cur][255];          // grand total
    }
    grid_bar(cnt, gen, CSRB);

    // ---- phase B3: final per-block scan -> off, cursor, dinv ----
    {
        const int d0 = in0 ? deg[idx0] : 0;
        const int d1 = in1 ? deg[idx1] : 0;
        const int s = d0 + d1;
        __shared__ int buf[2][256];
        buf[0][t] = s;
        __syncthreads();
        int cur = 0;
        for (int d2 = 1; d2 < 256; d2 <<= 1) {
            int x = buf[cur][t];
            if (t >= d2) x += buf[cur][t - d2];
            buf[cur ^ 1][t] = x;
            __syncthreads();
            cur ^= 1;
        }
        int base = bsum[bid] + buf[cur][t] - s;        // global exclusive prefix
        if (in0) {
            off[idx0] = base; cursor[idx0] = base;
            dinv[idx0] = rsqrtf((float)(d0 + 1));      // +1 self-loop
        }
        if (in1) {
            off[idx1] = base + d0; cursor[idx1] = base + d0;
            dinv[idx1] = rsqrtf((float)(d1 + 1));
        }
    }
    grid_bar(cnt, gen, CSRB);

    // ---- phase C: fill edge lists (CSR by dst, store src) ----
    if (i64) {
        const long long* sp = (const long long*)ei;
        const long long* dp = sp + E;
        for (int i = gtid; i < E; i += GT) {
            int s = (int)sp[i], d = (int)dp[i];
            int pos = atomicAdd(&cursor[d], 1);
            eidx[pos] = s;
        }
    } else {
        const int* sp = (const int*)ei;
        const int* dp = sp + E;
        for (int i = gtid; i < E; i += GT) {
            int s = sp[i], d = dp[i];
            int pos = atomicAdd(&cursor[d], 1);
            eidx[pos] = s;
        }
    }
}

// ===== MFMA GEMM: HS[m,:] = bf16( (X[m,:] @ W) * dinv[m] ), K=128 =====
template<int N>
__global__ __launch_bounds__(256) void gemm_mfma_k(
    const void* __restrict__ X, const uint4* __restrict__ wpk,
    const float* __restrict__ dinv, u16* __restrict__ HS,
    const int* __restrict__ flags, int x_is_ext, int M)
{
    constexpr int NT = N / 16;                  // n-tiles
    constexpr int NC8 = N / 8;                  // 16B chunks per output row
    __shared__ u32 xlds[128 * 64];              // 128 rows x 256B bf16 (32 KB)
    const int t = threadIdx.x;
    const int wave = t >> 6, lane = t & 63;
    const int q = lane >> 4, m = lane & 15;
    const bool xf32 = (x_is_ext != 0) && (flags[0] != 0);
    const int row0 = blockIdx.x * 128;

    // ---- stage X tile -> LDS (coalesced; 2048 chunks of 16B bf16) ----
    for (int c = t; c < 2048; c += 256) {
        const int row = c >> 4, c8 = c & 15;
        const int grow = row0 + row;
        uint4 pk = make_uint4(0u, 0u, 0u, 0u);
        if (grow < M) {
            if (xf32) {
                const float* xp = (const float*)X + (size_t)grow * 128 + c8 * 8;
                float4 u = *(const float4*)xp;
                float4 v = *(const float4*)(xp + 4);
                pk.x = packbf(u.x, u.y); pk.y = packbf(u.z, u.w);
                pk.z = packbf(v.x, v.y); pk.w = packbf(v.z, v.w);
            } else {
                pk = *(const uint4*)((const u16*)X + (size_t)grow * 128 + c8 * 8);
            }
        }
        *(uint4*)&xlds[row * 64 + c8 * 4] = pk;
    }
    __syncthreads();

    // ---- A-fragments from LDS (wave's own 32 rows) ----
    union { uint4 u; short8 v; } a[2][4];
    #pragma unroll
    for (int rt = 0; rt < 2; rt++)
        #pragma unroll
        for (int s = 0; s < 4; s++)
            a[rt][s].u = *(const uint4*)&xlds[(wave * 32 + rt * 16 + m) * 64 + (s * 4 + q) * 4];

    // ---- MFMA loop; B-frags direct from global wpk (L2-resident) ----
    f32x4 acc[2][NT];
    #pragma unroll
    for (int rt = 0; rt < 2; rt++)
        #pragma unroll
        for (int tt = 0; tt < NT; tt++)
            acc[rt][tt] = (f32x4){0.f, 0.f, 0.f, 0.f};

    #pragma unroll
    for (int s = 0; s < 4; s++) {
        union { uint4 u; short8 v; } b[NT];
        #pragma unroll
        for (int tt = 0; tt < NT; tt++)
            b[tt].u = wpk[(s * 4 + q) * N + tt * 16 + m];
        #pragma unroll
        for (int tt = 0; tt < NT; tt++)
            #pragma unroll
            for (int rt = 0; rt < 2; rt++)
                acc[rt][tt] = __builtin_amdgcn_mfma_f32_16x16x32_bf16(
                    a[rt][s].v, b[tt].v, acc[rt][tt], 0, 0, 0);
    }

    // ---- epilogue: dinv scale, repack via wave-private LDS, 16B stores ----
    float dv[2][4];
    #pragma unroll
    for (int rt = 0; rt < 2; rt++)
        #pragma unroll
        for (int r = 0; r < 4; r++) {
            const int grow = row0 + wave * 32 + rt * 16 + q * 4 + r;
            dv[rt][r] = (grow < M) ? dinv[grow] : 0.f;
        }

    u16* orow = (u16*)&xlds[wave * 32 * 64];    // wave-private 8KB region
    #pragma unroll
    for (int rt = 0; rt < 2; rt++)
        #pragma unroll
        for (int tt = 0; tt < NT; tt++)
            #pragma unroll
            for (int r = 0; r < 4; r++)
                orow[(rt * 16 + q * 4 + r) * N + tt * 16 + m] =
                    f2bf(acc[rt][tt][r] * dv[rt][r]);

    constexpr int ITER = 16 * NC8 / 64;         // 4 (N=128) / 2 (N=64)
    #pragma unroll
    for (int rt = 0; rt < 2; rt++) {
        #pragma unroll
        for (int j = 0; j < ITER; j++) {
            const int cc = lane + j * 64;
            const int lrow = cc / NC8, c8 = cc % NC8;
            const int grow = row0 + wave * 32 + rt * 16 + lrow;
            uint4 v = *(const uint4*)&((const u32*)orow)[(rt * 16 + lrow) * (N / 2) + c8 * 4];
            if (grow < M)
                *(uint4*)(HS + (size_t)grow * N + c8 * 8) = v;
        }
    }
}

// out[i,:] = act( dinv[i] * (sum_{j in N(i)} hs[j,:] + hs[i,:]) + bias )
// TPN = N/8 lanes/node, 16B gathers, 4-edge unroll for MLP.
template<int N, bool RELU>
__global__ __launch_bounds__(256) void aggregate_k(
    const u16* __restrict__ hs, const int* __restrict__ eidx,
    const int* __restrict__ off, const float* __restrict__ dinv,
    const void* __restrict__ bias, void* __restrict__ out,
    const int* __restrict__ flags, int out_is_ext, int M)
{
    constexpr int TPN = N / 8;               // threads per node, 8 cols each
    constexpr int NPB = 256 / TPN;
    const int node = blockIdx.x * NPB + threadIdx.x / TPN;
    const int lane = threadIdx.x % TPN;
    if (node >= M) return;
    const int f32io = flags[0];
    const int beg = off[node], end = off[node + 1];
    const int c8 = lane * 8;
    const u16* __restrict__ hrow = hs + c8;

    float a[8];
    {
        uint4 sp = *(const uint4*)(hrow + (size_t)node * N);   // self-loop term
        const u16* s = (const u16*)&sp;
        #pragma unroll
        for (int j = 0; j < 8; j++) a[j] = bf2f(s[j]);
    }

    int p = beg;
    for (; p + 4 <= end; p += 4) {
        const int s0 = eidx[p + 0], s1 = eidx[p + 1];
        const int s2 = eidx[p + 2], s3 = eidx[p + 3];
        uint4 v0 = *(const uint4*)(hrow + (size_t)s0 * N);
        uint4 v1 = *(const uint4*)(hrow + (size_t)s1 * N);
        uint4 v2 = *(const uint4*)(hrow + (size_t)s2 * N);
        uint4 v3 = *(const uint4*)(hrow + (size_t)s3 * N);
        const u16* q0 = (const u16*)&v0; const u16* q1 = (const u16*)&v1;
        const u16* q2 = (const u16*)&v2; const u16* q3 = (const u16*)&v3;
        #pragma unroll
        for (int j = 0; j < 8; j++)
            a[j] += (bf2f(q0[j]) + bf2f(q1[j])) + (bf2f(q2[j]) + bf2f(q3[j]));
    }
    for (; p < end; p++) {
        const int s = eidx[p];
        uint4 v = *(const uint4*)(hrow + (size_t)s * N);
        const u16* q = (const u16*)&v;
        #pragma unroll
        for (int j = 0; j < 8; j++) a[j] += bf2f(q[j]);
    }

    const float dv = dinv[node];
    float b[8];
    if (f32io) {
        float4 u = *(const float4*)((const float*)bias + c8);
        float4 v = *(const float4*)((const float*)bias + c8 + 4);
        b[0] = u.x; b[1] = u.y; b[2] = u.z; b[3] = u.w;
        b[4] = v.x; b[5] = v.y; b[6] = v.z; b[7] = v.w;
    } else {
        uint4 u = *(const uint4*)((const u16*)bias + c8);
        const u16* s = (const u16*)&u;
        #pragma unroll
        for (int j = 0; j < 8; j++) b[j] = bf2f(s[j]);
    }
    float o[8];
    #pragma unroll
    for (int j = 0; j < 8; j++) {
        o[j] = fmaf(dv, a[j], b[j]);
        if (RELU) o[j] = fmaxf(o[j], 0.f);
    }
    if (out_is_ext && f32io) {
        float* op = (float*)out + (size_t)node * N + c8;
        *(float4*)op       = make_float4(o[0], o[1], o[2], o[3]);
        *(float4*)(op + 4) = make_float4(o[4], o[5], o[6], o[7]);
    } else {
        uint4 pk;
        pk.x = packbf(o[0], o[1]); pk.y = packbf(o[2], o[3]);
        pk.z = packbf(o[4], o[5]); pk.w = packbf(o[6], o[7]);
        *(uint4*)((u16*)out + (size_t)node * N + c8) = pk;
    }
}

extern "C" void kernel_launch(void* const* d_in, const int* in_sizes, int n_in,
                              void* d_out, int out_size, void* d_ws, size_t ws_size,
                              hipStream_t stream) {
    const void* x  = d_in[0];
    const void* ei = d_in[1];
    const void* W1 = d_in[2];
    const void* b1 = d_in[3];
    const void* W2 = d_in[4];
    const void* b2 = d_in[5];

    const int M = in_sizes[0] / 128;   // 100000 nodes
    const int E = in_sizes[1] / 2;     // 600000 edges

    char* ws = (char*)d_ws;
    size_t offb = 0;
    auto alloc = [&](size_t bytes) -> void* {
        void* p = ws + offb; offb += (bytes + 255) & ~(size_t)255; return p;
    };
    int*   flags  = (int*)  alloc(256);
    int*   bsum   = (int*)  alloc(1024);
    uint4* wpk1   = (uint4*)alloc(16 * 128 * 16);         // 32 KB packed W1
    uint4* wpk2   = (uint4*)alloc(16 * 64 * 16);          // 16 KB packed W2
    int*   deg    = (int*)  alloc((size_t)M * 4);
    int*   off    = (int*)  alloc((size_t)(M + 1) * 4);
    int*   cursor = (int*)  alloc((size_t)M * 4);
    float* dinv   = (float*)alloc((size_t)M * 4);
    int*   eidx   = (int*)  alloc((size_t)E * 4);
    u16*   hs1    = (u16*)  alloc((size_t)M * 128 * 2);   // 25.6 MB
    u16*   out1   = (u16*)  alloc((size_t)M * 128 * 2);   // 25.6 MB (z = relu layer-1 out)
    u16*   hs2    = (u16*)  alloc((size_t)M * 64 * 2);    // 12.8 MB
    (void)ws_size; (void)n_in; (void)out_size;

    // 1: dtype detect + zero deg + zero barrier words
    detect_zero_k<<<(M + 1023) / 1024, 256, 0, stream>>>((const u32*)x, (const u32*)ei,
                                                         flags, deg, M);
    // 2: fused CSR build (wpack + count + scan + fill) with grid barriers
    csr_build_k<<<CSRB, 256, 0, stream>>>(ei, E, M, flags, W1, W2, wpk1, wpk2,
                                          deg, bsum, off, cursor, dinv, eidx);
    // 3: hs1 = (x @ W1) * dinv
    gemm_mfma_k<128><<<(M + 127) / 128, 256, 0, stream>>>(x, wpk1, dinv, hs1, flags, 1, M);
    // 4: z = relu(dinv*agg(hs1) + b1)
    aggregate_k<128, true><<<(M + 15) / 16, 256, 0, stream>>>(hs1, eidx, off, dinv, b1, out1,
                                                              flags, 0, M);
    // 5: hs2 = (z @ W2) * dinv
    gemm_mfma_k<64><<<(M + 127) / 128, 256, 0, stream>>>(out1, wpk2, dinv, hs2, flags, 0, M);
    // 6: out = dinv*agg(hs2) + b2
    aggregate_k<64, false><<<(M + 31) / 32, 256, 0, stream>>>(hs2, eidx, off, dinv, b2, d_out,
                                                              flags, 1, M);
}

// Round 9
// 243.136 us; speedup vs baseline: 1.5048x; 1.5048x over previous
//
#include <hip/hip_runtime.h>
#include <hip/hip_bf16.h>
#include <stdint.h>

typedef unsigned int u32;
typedef unsigned short u16;
typedef __attribute__((ext_vector_type(8))) short short8;   // 8 bf16 = 4 VGPRs (MFMA A/B frag)
typedef __attribute__((ext_vector_type(4))) float f32x4;    // MFMA C/D frag

#define SCAN_TILE 2048   // elements per block in hierarchical scan (256 thr x 8)

__device__ __forceinline__ float bf2f(u16 u) {
    union { u32 u; float f; } v; v.u = ((u32)u) << 16; return v.f;
}
__device__ __forceinline__ u16 f2bf(float f) {
    u32 u = __float_as_uint(f);
    u32 r = (u + 0x7FFFu + ((u >> 16) & 1u)) >> 16;  // RNE
    return (u16)r;
}
__device__ __forceinline__ u32 packbf(float lo, float hi) {
    return ((u32)f2bf(hi) << 16) | (u32)f2bf(lo);
}

// Block 0: flags[0]=1 if float tensors are f32 (else bf16), flags[1]=1 if
// edge_index int64 (else int32). ALL blocks: zero deg[0..M).
__global__ __launch_bounds__(256) void detect_zero_k(const u32* __restrict__ xw,
                                                     const u32* __restrict__ ew,
                                                     int* __restrict__ flags,
                                                     int* __restrict__ deg, int M) {
    const int t = threadIdx.x;
    const int i4 = (blockIdx.x * 256 + t) * 4;
    if (i4 + 4 <= M) *(int4*)(deg + i4) = make_int4(0, 0, 0, 0);
    else { for (int j = 0; j < 4; j++) if (i4 + j < M) deg[i4 + j] = 0; }

    if (blockIdx.x == 0) {
        __shared__ int cnt;
        __shared__ u32 orr;
        if (t == 0) { cnt = 0; orr = 0u; }
        __syncthreads();
        int hits = 0;
        for (int i = t; i < 1024; i += 256) {
            u32 f = (xw[i] >> 7) & 0xFFu;
            if (f >= 100u && f <= 140u) hits++;
        }
        atomicAdd(&cnt, hits);
        atomicOr(&orr, ew[2 * t + 1]);
        __syncthreads();
        if (t == 0) {
            flags[0] = (cnt < 512) ? 1 : 0;
            flags[1] = (orr == 0u) ? 1 : 0;
        }
    }
}

// Pre-pack W into B-frag order: chunk p = kb*N+n holds 8 bf16 of col n,
// rows k = kb*8..+7.
template<int N>
__device__ __forceinline__ void wpack_one(const void* W, uint4* wpk, int p, int f32w) {
    const int n = p & (N - 1);
    const int kb = p >> ((N == 128) ? 7 : 6);
    u32 pk[4];
    if (f32w) {
        const float* wp = (const float*)W + (size_t)(kb * 8) * N + n;
        #pragma unroll
        for (int jj = 0; jj < 4; jj++)
            pk[jj] = packbf(wp[(2 * jj) * N], wp[(2 * jj + 1) * N]);
    } else {
        const u16* wp = (const u16*)W + (size_t)(kb * 8) * N + n;
        #pragma unroll
        for (int jj = 0; jj < 4; jj++)
            pk[jj] = ((u32)wp[(2 * jj + 1) * N] << 16) | (u32)wp[(2 * jj) * N];
    }
    uint4 v; v.x = pk[0]; v.y = pk[1]; v.z = pk[2]; v.w = pk[3];
    wpk[p] = v;
}

// blocks 0..7: W1 (128x128); blocks 8..11: W2 (128x64)
__global__ __launch_bounds__(256) void wpack_all_k(const void* __restrict__ W1,
                                                   const void* __restrict__ W2,
                                                   uint4* __restrict__ wpk1,
                                                   uint4* __restrict__ wpk2,
                                                   const int* __restrict__ flags) {
    const int b = blockIdx.x, t = threadIdx.x;
    const int f32w = flags[0];
    if (b < 8) wpack_one<128>(W1, wpk1, b * 256 + t, f32w);
    else       wpack_one<64> (W2, wpk2, (b - 8) * 256 + t, f32w);
}

// 2 edges per thread, 16B index loads
__global__ __launch_bounds__(256) void count_deg_k(const void* __restrict__ ei, int E,
                                                   const int* __restrict__ flags,
                                                   int* __restrict__ deg) {
    const int i2 = (blockIdx.x * 256 + threadIdx.x) * 2;
    if (i2 >= E) return;
    if (flags[1]) {
        const long long* dp = (const long long*)ei + E;
        if (i2 + 1 < E) {
            longlong2 v = *(const longlong2*)(dp + i2);
            atomicAdd(&deg[(int)v.x], 1);
            atomicAdd(&deg[(int)v.y], 1);
        } else atomicAdd(&deg[(int)dp[i2]], 1);
    } else {
        const int* dp = (const int*)ei + E;
        if (i2 + 1 < E) {
            int2 v = *(const int2*)(dp + i2);
            atomicAdd(&deg[v.x], 1);
            atomicAdd(&deg[v.y], 1);
        } else atomicAdd(&deg[dp[i2]], 1);
    }
}

// ---- hierarchical exclusive scan of deg[0..M) -> off/cursor, plus dinv ----
__global__ __launch_bounds__(256) void scan_partial_k(const int* __restrict__ deg, int M,
                                                      int* __restrict__ bsum) {
    const int t = threadIdx.x;
    const int base = blockIdx.x * SCAN_TILE + t * 8;
    int s = 0;
    if (base + 8 <= M) {
        int4 a = *(const int4*)(deg + base);
        int4 b = *(const int4*)(deg + base + 4);
        s = a.x + a.y + a.z + a.w + b.x + b.y + b.z + b.w;
    } else {
        for (int j = 0; j < 8; j++) if (base + j < M) s += deg[base + j];
    }
    __shared__ int red[256];
    red[t] = s;
    __syncthreads();
    for (int d = 128; d > 0; d >>= 1) {
        if (t < d) red[t] += red[t + d];
        __syncthreads();
    }
    if (t == 0) bsum[blockIdx.x] = red[0];
}

__global__ __launch_bounds__(256) void scan_bsum_k(int* __restrict__ bsum, int nb,
                                                   int* __restrict__ off, int M) {
    __shared__ int buf[2][256];
    const int t = threadIdx.x;
    int v = (t < nb) ? bsum[t] : 0;
    const int own = v;
    buf[0][t] = v;
    __syncthreads();
    int cur = 0;
    for (int d = 1; d < 256; d <<= 1) {
        int x = buf[cur][t];
        if (t >= d) x += buf[cur][t - d];
        buf[cur ^ 1][t] = x;
        __syncthreads();
        cur ^= 1;
    }
    if (t < nb) bsum[t] = buf[cur][t] - own;          // exclusive
    if (t == 255) off[M] = buf[cur][255];             // grand total
}

__global__ __launch_bounds__(256) void scan_final_k(const int* __restrict__ deg,
                                                    const int* __restrict__ bsum, int M,
                                                    int* __restrict__ off,
                                                    int* __restrict__ cursor,
                                                    float* __restrict__ dinv) {
    const int t = threadIdx.x;
    const int base = blockIdx.x * SCAN_TILE + t * 8;
    int v[8];
    int s = 0;
    const bool full = (base + 8 <= M);
    if (full) {
        int4 a = *(const int4*)(deg + base);
        int4 b = *(const int4*)(deg + base + 4);
        v[0] = a.x; v[1] = a.y; v[2] = a.z; v[3] = a.w;
        v[4] = b.x; v[5] = b.y; v[6] = b.z; v[7] = b.w;
        s = v[0] + v[1] + v[2] + v[3] + v[4] + v[5] + v[6] + v[7];
    } else {
        #pragma unroll
        for (int j = 0; j < 8; j++) { v[j] = (base + j < M) ? deg[base + j] : 0; s += v[j]; }
    }
    __shared__ int buf[2][256];
    buf[0][t] = s;
    __syncthreads();
    int cur = 0;
    for (int d = 1; d < 256; d <<= 1) {
        int x = buf[cur][t];
        if (t >= d) x += buf[cur][t - d];
        buf[cur ^ 1][t] = x;
        __syncthreads();
        cur ^= 1;
    }
    int pre = bsum[blockIdx.x] + buf[cur][t] - s;
    int o[8]; float dv[8];
    #pragma unroll
    for (int j = 0; j < 8; j++) {
        o[j] = pre;
        dv[j] = rsqrtf((float)(v[j] + 1));            // +1 self-loop
        pre += v[j];
    }
    if (full) {
        *(int4*)(off + base)     = make_int4(o[0], o[1], o[2], o[3]);
        *(int4*)(off + base + 4) = make_int4(o[4], o[5], o[6], o[7]);
        *(int4*)(cursor + base)     = make_int4(o[0], o[1], o[2], o[3]);
        *(int4*)(cursor + base + 4) = make_int4(o[4], o[5], o[6], o[7]);
        *(float4*)(dinv + base)     = make_float4(dv[0], dv[1], dv[2], dv[3]);
        *(float4*)(dinv + base + 4) = make_float4(dv[4], dv[5], dv[6], dv[7]);
    } else {
        for (int j = 0; j < 8; j++) if (base + j < M) {
            off[base + j] = o[j]; cursor[base + j] = o[j]; dinv[base + j] = dv[j];
        }
    }
}

// 2 edges per thread, 16B index loads
__global__ __launch_bounds__(256) void fill_k(const void* __restrict__ ei, int E,
                                              const int* __restrict__ flags,
                                              int* __restrict__ cursor, int* __restrict__ eidx) {
    const int i2 = (blockIdx.x * 256 + threadIdx.x) * 2;
    if (i2 >= E) return;
    int s0, d0, s1 = -1, d1 = -1;
    if (flags[1]) {
        const long long* sp = (const long long*)ei;
        const long long* dp = sp + E;
        if (i2 + 1 < E) {
            longlong2 sv = *(const longlong2*)(sp + i2);
            longlong2 dv = *(const longlong2*)(dp + i2);
            s0 = (int)sv.x; s1 = (int)sv.y; d0 = (int)dv.x; d1 = (int)dv.y;
        } else { s0 = (int)sp[i2]; d0 = (int)dp[i2]; }
    } else {
        const int* sp = (const int*)ei;
        const int* dp = sp + E;
        if (i2 + 1 < E) {
            int2 sv = *(const int2*)(sp + i2);
            int2 dv = *(const int2*)(dp + i2);
            s0 = sv.x; s1 = sv.y; d0 = dv.x; d1 = dv.y;
        } else { s0 = sp[i2]; d0 = dp[i2]; }
    }
    int p0 = atomicAdd(&cursor[d0], 1);
    eidx[p0] = s0;
    if (s1 >= 0 || d1 >= 0) {
        if (i2 + 1 < E) {
            int p1 = atomicAdd(&cursor[d1], 1);
            eidx[p1] = s1;
        }
    }
}

// ===== MFMA GEMM v3: 64 rows/block (4 waves x 16 rows), 16KB LDS =====
// HS[m,:] = bf16( (X[m,:] @ W) * dinv[m] ), K=128. B-frags from pre-packed
// global wpk (L2-resident). Smaller tile -> ~2x resident blocks/CU vs v2.
template<int N>
__global__ __launch_bounds__(256) void gemm_mfma_k(
    const void* __restrict__ X, const uint4* __restrict__ wpk,
    const float* __restrict__ dinv, u16* __restrict__ HS,
    const int* __restrict__ flags, int x_is_ext, int M)
{
    constexpr int NT = N / 16;                  // n-tiles
    constexpr int NC8 = N / 8;                  // 16B chunks per output row
    __shared__ u32 xlds[64 * 64];               // 64 rows x 256B bf16 (16 KB)
    const int t = threadIdx.x;
    const int wave = t >> 6, lane = t & 63;
    const int q = lane >> 4, m = lane & 15;
    const bool xf32 = (x_is_ext != 0) && (flags[0] != 0);
    const int row0 = blockIdx.x * 64;

    // ---- stage X tile -> LDS (coalesced; 1024 chunks of 16B bf16) ----
    for (int c = t; c < 1024; c += 256) {
        const int row = c >> 4, c8 = c & 15;
        const int grow = row0 + row;
        uint4 pk = make_uint4(0u, 0u, 0u, 0u);
        if (grow < M) {
            if (xf32) {
                const float* xp = (const float*)X + (size_t)grow * 128 + c8 * 8;
                float4 u = *(const float4*)xp;
                float4 v = *(const float4*)(xp + 4);
                pk.x = packbf(u.x, u.y); pk.y = packbf(u.z, u.w);
                pk.z = packbf(v.x, v.y); pk.w = packbf(v.z, v.w);
            } else {
                pk = *(const uint4*)((const u16*)X + (size_t)grow * 128 + c8 * 8);
            }
        }
        *(uint4*)&xlds[row * 64 + c8 * 4] = pk;
    }
    __syncthreads();

    // ---- A-fragments from LDS (wave's own 16 rows) ----
    union { uint4 u; short8 v; } a[4];
    #pragma unroll
    for (int s = 0; s < 4; s++)
        a[s].u = *(const uint4*)&xlds[(wave * 16 + m) * 64 + (s * 4 + q) * 4];

    // ---- MFMA loop; B-frags direct from global wpk (L2-resident) ----
    f32x4 acc[NT];
    #pragma unroll
    for (int tt = 0; tt < NT; tt++)
        acc[tt] = (f32x4){0.f, 0.f, 0.f, 0.f};

    #pragma unroll
    for (int s = 0; s < 4; s++) {
        union { uint4 u; short8 v; } b[NT];
        #pragma unroll
        for (int tt = 0; tt < NT; tt++)
            b[tt].u = wpk[(s * 4 + q) * N + tt * 16 + m];
        #pragma unroll
        for (int tt = 0; tt < NT; tt++)
            acc[tt] = __builtin_amdgcn_mfma_f32_16x16x32_bf16(
                a[s].v, b[tt].v, acc[tt], 0, 0, 0);
    }

    // ---- epilogue: dinv scale, repack via wave-private LDS, 16B stores ----
    float dv[4];
    #pragma unroll
    for (int r = 0; r < 4; r++) {
        const int grow = row0 + wave * 16 + q * 4 + r;
        dv[r] = (grow < M) ? dinv[grow] : 0.f;
    }

    u16* orow = (u16*)&xlds[wave * 16 * 64];    // wave-private 4KB region
    #pragma unroll
    for (int tt = 0; tt < NT; tt++)
        #pragma unroll
        for (int r = 0; r < 4; r++)
            orow[(q * 4 + r) * N + tt * 16 + m] = f2bf(acc[tt][r] * dv[r]);

    constexpr int ITER = 16 * NC8 / 64;         // 4 (N=128) / 2 (N=64)
    #pragma unroll
    for (int j = 0; j < ITER; j++) {
        const int cc = lane + j * 64;
        const int lrow = cc / NC8, c8 = cc % NC8;
        const int grow = row0 + wave * 16 + lrow;
        uint4 v = *(const uint4*)&((const u32*)orow)[lrow * (N / 2) + c8 * 4];
        if (grow < M)
            *(uint4*)(HS + (size_t)grow * N + c8 * 8) = v;
    }
}

// out[i,:] = act( dinv[i] * (sum_{j in N(i)} hs[j,:] + hs[i,:]) + bias )
// TPN = N/8 lanes/node, 16B gathers, 4-edge unroll for MLP.
template<int N, bool RELU>
__global__ __launch_bounds__(256) void aggregate_k(
    const u16* __restrict__ hs, const int* __restrict__ eidx,
    const int* __restrict__ off, const float* __restrict__ dinv,
    const void* __restrict__ bias, void* __restrict__ out,
    const int* __restrict__ flags, int out_is_ext, int M)
{
    constexpr int TPN = N / 8;               // threads per node, 8 cols each
    constexpr int NPB = 256 / TPN;
    const int node = blockIdx.x * NPB + threadIdx.x / TPN;
    const int lane = threadIdx.x % TPN;
    if (node >= M) return;
    const int f32io = flags[0];
    const int beg = off[node], end = off[node + 1];
    const int c8 = lane * 8;
    const u16* __restrict__ hrow = hs + c8;

    float a[8];
    {
        uint4 sp = *(const uint4*)(hrow + (size_t)node * N);   // self-loop term
        const u16* s = (const u16*)&sp;
        #pragma unroll
        for (int j = 0; j < 8; j++) a[j] = bf2f(s[j]);
    }

    int p = beg;
    for (; p + 4 <= end; p += 4) {
        const int s0 = eidx[p + 0], s1 = eidx[p + 1];
        const int s2 = eidx[p + 2], s3 = eidx[p + 3];
        uint4 v0 = *(const uint4*)(hrow + (size_t)s0 * N);
        uint4 v1 = *(const uint4*)(hrow + (size_t)s1 * N);
        uint4 v2 = *(const uint4*)(hrow + (size_t)s2 * N);
        uint4 v3 = *(const uint4*)(hrow + (size_t)s3 * N);
        const u16* q0 = (const u16*)&v0; const u16* q1 = (const u16*)&v1;
        const u16* q2 = (const u16*)&v2; const u16* q3 = (const u16*)&v3;
        #pragma unroll
        for (int j = 0; j < 8; j++)
            a[j] += (bf2f(q0[j]) + bf2f(q1[j])) + (bf2f(q2[j]) + bf2f(q3[j]));
    }
    for (; p < end; p++) {
        const int s = eidx[p];
        uint4 v = *(const uint4*)(hrow + (size_t)s * N);
        const u16* q = (const u16*)&v;
        #pragma unroll
        for (int j = 0; j < 8; j++) a[j] += bf2f(q[j]);
    }

    const float dv = dinv[node];
    float b[8];
    if (f32io) {
        float4 u = *(const float4*)((const float*)bias + c8);
        float4 v = *(const float4*)((const float*)bias + c8 + 4);
        b[0] = u.x; b[1] = u.y; b[2] = u.z; b[3] = u.w;
        b[4] = v.x; b[5] = v.y; b[6] = v.z; b[7] = v.w;
    } else {
        uint4 u = *(const uint4*)((const u16*)bias + c8);
        const u16* s = (const u16*)&u;
        #pragma unroll
        for (int j = 0; j < 8; j++) b[j] = bf2f(s[j]);
    }
    float o[8];
    #pragma unroll
    for (int j = 0; j < 8; j++) {
        o[j] = fmaf(dv, a[j], b[j]);
        if (RELU) o[j] = fmaxf(o[j], 0.f);
    }
    if (out_is_ext && f32io) {
        float* op = (float*)out + (size_t)node * N + c8;
        *(float4*)op       = make_float4(o[0], o[1], o[2], o[3]);
        *(float4*)(op + 4) = make_float4(o[4], o[5], o[6], o[7]);
    } else {
        uint4 pk;
        pk.x = packbf(o[0], o[1]); pk.y = packbf(o[2], o[3]);
        pk.z = packbf(o[4], o[5]); pk.w = packbf(o[6], o[7]);
        *(uint4*)((u16*)out + (size_t)node * N + c8) = pk;
    }
}

extern "C" void kernel_launch(void* const* d_in, const int* in_sizes, int n_in,
                              void* d_out, int out_size, void* d_ws, size_t ws_size,
                              hipStream_t stream) {
    const void* x  = d_in[0];
    const void* ei = d_in[1];
    const void* W1 = d_in[2];
    const void* b1 = d_in[3];
    const void* W2 = d_in[4];
    const void* b2 = d_in[5];

    const int M = in_sizes[0] / 128;   // 100000 nodes
    const int E = in_sizes[1] / 2;     // 600000 edges
    const int NB = (M + SCAN_TILE - 1) / SCAN_TILE;

    char* ws = (char*)d_ws;
    size_t offb = 0;
    auto alloc = [&](size_t bytes) -> void* {
        void* p = ws + offb; offb += (bytes + 255) & ~(size_t)255; return p;
    };
    int*   flags  = (int*)  alloc(256);
    int*   bsum   = (int*)  alloc(1024);
    uint4* wpk1   = (uint4*)alloc(16 * 128 * 16);         // 32 KB packed W1
    uint4* wpk2   = (uint4*)alloc(16 * 64 * 16);          // 16 KB packed W2
    int*   deg    = (int*)  alloc((size_t)M * 4);
    int*   off    = (int*)  alloc((size_t)(M + 1) * 4);
    int*   cursor = (int*)  alloc((size_t)M * 4);
    float* dinv   = (float*)alloc((size_t)M * 4);
    int*   eidx   = (int*)  alloc((size_t)E * 4);
    u16*   hs1    = (u16*)  alloc((size_t)M * 128 * 2);   // 25.6 MB
    u16*   out1   = (u16*)  alloc((size_t)M * 128 * 2);   // 25.6 MB (z = relu layer-1 out)
    u16*   hs2    = (u16*)  alloc((size_t)M * 64 * 2);    // 12.8 MB
    (void)ws_size; (void)n_in; (void)out_size;

    // 1: dtype detect + zero deg
    detect_zero_k<<<(M + 1023) / 1024, 256, 0, stream>>>((const u32*)x, (const u32*)ei,
                                                         flags, deg, M);
    // 2: pack both weights
    wpack_all_k<<<12, 256, 0, stream>>>(W1, W2, wpk1, wpk2, flags);
    // 3-6: CSR build
    count_deg_k<<<(E + 511) / 512, 256, 0, stream>>>(ei, E, flags, deg);
    scan_partial_k<<<NB, 256, 0, stream>>>(deg, M, bsum);
    scan_bsum_k<<<1, 256, 0, stream>>>(bsum, NB, off, M);
    scan_final_k<<<NB, 256, 0, stream>>>(deg, bsum, M, off, cursor, dinv);
    fill_k<<<(E + 511) / 512, 256, 0, stream>>>(ei, E, flags, cursor, eidx);

    // 7: hs1 = (x @ W1) * dinv
    gemm_mfma_k<128><<<(M + 63) / 64, 256, 0, stream>>>(x, wpk1, dinv, hs1, flags, 1, M);
    // 8: z = relu(dinv*agg(hs1) + b1)
    aggregate_k<128, true><<<(M + 15) / 16, 256, 0, stream>>>(hs1, eidx, off, dinv, b1, out1,
                                                              flags, 0, M);
    // 9: hs2 = (z @ W2) * dinv
    gemm_mfma_k<64><<<(M + 63) / 64, 256, 0, stream>>>(out1, wpk2, dinv, hs2, flags, 0, M);
    // 10: out = dinv*agg(hs2) + b2
    aggregate_k<64, false><<<(M + 31) / 32, 256, 0, stream>>>(hs2, eidx, off, dinv, b2, d_out,
                                                              flags, 1, M);
}

// Round 10
// 242.702 us; speedup vs baseline: 1.5075x; 1.0018x over previous
//
#include <hip/hip_runtime.h>
#include <hip/hip_bf16.h>
#include <stdint.h>

typedef unsigned int u32;
typedef unsigned short u16;
typedef unsigned long long u64;
typedef __attribute__((ext_vector_type(8))) short short8;   // 8 bf16 = 4 VGPRs (MFMA A/B frag)
typedef __attribute__((ext_vector_type(4))) float f32x4;    // MFMA C/D frag

#define SCAN_TILE 2048   // elements per block in lookback scan (256 thr x 8)

__device__ __forceinline__ float bf2f(u16 u) {
    union { u32 u; float f; } v; v.u = ((u32)u) << 16; return v.f;
}
__device__ __forceinline__ u16 f2bf(float f) {
    u32 u = __float_as_uint(f);
    u32 r = (u + 0x7FFFu + ((u >> 16) & 1u)) >> 16;  // RNE
    return (u16)r;
}
__device__ __forceinline__ u32 packbf(float lo, float hi) {
    return ((u32)f2bf(hi) << 16) | (u32)f2bf(lo);
}

// Pre-pack W into B-frag order: chunk p = kb*N+n holds 8 bf16 of col n,
// rows k = kb*8..+7.
template<int N>
__device__ __forceinline__ void wpack_one(const void* W, uint4* wpk, int p, int f32w) {
    const int n = p & (N - 1);
    const int kb = p >> ((N == 128) ? 7 : 6);
    u32 pk[4];
    if (f32w) {
        const float* wp = (const float*)W + (size_t)(kb * 8) * N + n;
        #pragma unroll
        for (int jj = 0; jj < 4; jj++)
            pk[jj] = packbf(wp[(2 * jj) * N], wp[(2 * jj + 1) * N]);
    } else {
        const u16* wp = (const u16*)W + (size_t)(kb * 8) * N + n;
        #pragma unroll
        for (int jj = 0; jj < 4; jj++)
            pk[jj] = ((u32)wp[(2 * jj + 1) * N] << 16) | (u32)wp[(2 * jj) * N];
    }
    uint4 v; v.x = pk[0]; v.y = pk[1]; v.z = pk[2]; v.w = pk[3];
    wpk[p] = v;
}

// ALL blocks: zero deg slice. Block 0: flags + zero lookback words.
// Blocks 0..11: local f32-detect on x (self-contained) + wpack W1/W2.
__global__ __launch_bounds__(256) void prep_k(const u32* __restrict__ xw,
                                              const u32* __restrict__ ew,
                                              int* __restrict__ flags,
                                              int* __restrict__ deg, int M,
                                              const void* __restrict__ W1,
                                              const void* __restrict__ W2,
                                              uint4* __restrict__ wpk1,
                                              uint4* __restrict__ wpk2,
                                              u64* __restrict__ lk, int nlk) {
    const int b = blockIdx.x, t = threadIdx.x;
    const int i4 = (b * 256 + t) * 4;
    if (i4 + 4 <= M) *(int4*)(deg + i4) = make_int4(0, 0, 0, 0);
    else { for (int j = 0; j < 4; j++) if (i4 + j < M) deg[i4 + j] = 0; }

    if (b < 12) {
        // local dtype detect on x's first 1024 words (block-private)
        __shared__ int cnt;
        if (t == 0) cnt = 0;
        __syncthreads();
        int hits = 0;
        #pragma unroll
        for (int j = 0; j < 4; j++) {
            u32 f = (xw[t * 4 + j] >> 7) & 0xFFu;
            if (f >= 100u && f <= 140u) hits++;
        }
        atomicAdd(&cnt, hits);
        __syncthreads();
        const int f32w = (cnt < 512) ? 1 : 0;
        if (b < 8) wpack_one<128>(W1, wpk1, b * 256 + t, f32w);
        else       wpack_one<64> (W2, wpk2, (b - 8) * 256 + t, f32w);
        if (b == 0) {
            if (t < nlk) lk[t] = 0ull;               // zero lookback words (poison=0xAA!)
            if (t == 0) flags[0] = f32w;
            // int64 edge detect: OR of hi-words (int64) vs values (int32)
            __shared__ u32 orr;
            if (t == 0) orr = 0u;
            __syncthreads();
            atomicOr(&orr, ew[2 * t + 1]);
            __syncthreads();
            if (t == 0) flags[1] = (orr == 0u) ? 1 : 0;
        }
    }
}

// 2 edges per thread, 16B index loads
__global__ __launch_bounds__(256) void count_deg_k(const void* __restrict__ ei, int E,
                                                   const int* __restrict__ flags,
                                                   int* __restrict__ deg) {
    const int i2 = (blockIdx.x * 256 + threadIdx.x) * 2;
    if (i2 >= E) return;
    if (flags[1]) {
        const long long* dp = (const long long*)ei + E;
        if (i2 + 1 < E) {
            longlong2 v = *(const longlong2*)(dp + i2);
            atomicAdd(&deg[(int)v.x], 1);
            atomicAdd(&deg[(int)v.y], 1);
        } else atomicAdd(&deg[(int)dp[i2]], 1);
    } else {
        const int* dp = (const int*)ei + E;
        if (i2 + 1 < E) {
            int2 v = *(const int2*)(dp + i2);
            atomicAdd(&deg[v.x], 1);
            atomicAdd(&deg[v.y], 1);
        } else atomicAdd(&deg[dp[i2]], 1);
    }
}

// ===== single-pass decoupled-lookback scan: deg -> off/cursor/dinv =====
// lk[b] packs (state<<62)|value: state 1=aggregate-ready, 2=prefix-ready.
// Values (<=E=600k) fit 32 bits. One u64 agent-scope atomic per publish —
// no fences, no global barrier (R8 lesson: device-fence barriers cost ~50us).
__global__ __launch_bounds__(256) void scan_lb_k(const int* __restrict__ deg, int M,
                                                 u64* __restrict__ lk,
                                                 int* __restrict__ off,
                                                 int* __restrict__ cursor,
                                                 float* __restrict__ dinv, int nb) {
    const int bid = blockIdx.x, t = threadIdx.x;
    const int base = bid * SCAN_TILE + t * 8;
    int v[8];
    int s = 0;
    const bool full = (base + 8 <= M);
    if (full) {
        int4 a = *(const int4*)(deg + base);
        int4 b = *(const int4*)(deg + base + 4);
        v[0] = a.x; v[1] = a.y; v[2] = a.z; v[3] = a.w;
        v[4] = b.x; v[5] = b.y; v[6] = b.z; v[7] = b.w;
        s = v[0] + v[1] + v[2] + v[3] + v[4] + v[5] + v[6] + v[7];
    } else {
        #pragma unroll
        for (int j = 0; j < 8; j++) { v[j] = (base + j < M) ? deg[base + j] : 0; s += v[j]; }
    }
    __shared__ int buf[2][256];
    buf[0][t] = s;
    __syncthreads();
    int cur = 0;
    for (int d = 1; d < 256; d <<= 1) {
        int x = buf[cur][t];
        if (t >= d) x += buf[cur][t - d];
        buf[cur ^ 1][t] = x;
        __syncthreads();
        cur ^= 1;
    }
    const int incl = buf[cur][t];          // inclusive prefix of per-thread sums
    const int btotal = buf[cur][255];      // block total

    __shared__ int sbase;
    if (t == 0) {
        if (bid == 0) {
            __hip_atomic_store(&lk[0], (2ull << 62) | (u32)btotal,
                               __ATOMIC_RELEASE, __HIP_MEMORY_SCOPE_AGENT);
            sbase = 0;
        } else {
            __hip_atomic_store(&lk[bid], (1ull << 62) | (u32)btotal,
                               __ATOMIC_RELEASE, __HIP_MEMORY_SCOPE_AGENT);
            int run = 0;
            int j = bid - 1;
            while (j >= 0) {
                u64 w = __hip_atomic_load(&lk[j], __ATOMIC_ACQUIRE,
                                          __HIP_MEMORY_SCOPE_AGENT);
                const u64 st = w >> 62;
                if (st == 0) { __builtin_amdgcn_s_sleep(1); continue; }
                run += (int)(w & 0xFFFFFFFFull);
                if (st == 2ull) break;
                j--;
            }
            sbase = run;
            __hip_atomic_store(&lk[bid], (2ull << 62) | (u32)(run + btotal),
                               __ATOMIC_RELEASE, __HIP_MEMORY_SCOPE_AGENT);
        }
    }
    __syncthreads();

    int pre = sbase + incl - s;            // global exclusive prefix at base
    int o[8]; float dv[8];
    #pragma unroll
    for (int j = 0; j < 8; j++) {
        o[j] = pre;
        dv[j] = rsqrtf((float)(v[j] + 1));            // +1 self-loop
        pre += v[j];
    }
    if (full) {
        *(int4*)(off + base)     = make_int4(o[0], o[1], o[2], o[3]);
        *(int4*)(off + base + 4) = make_int4(o[4], o[5], o[6], o[7]);
        *(int4*)(cursor + base)     = make_int4(o[0], o[1], o[2], o[3]);
        *(int4*)(cursor + base + 4) = make_int4(o[4], o[5], o[6], o[7]);
        *(float4*)(dinv + base)     = make_float4(dv[0], dv[1], dv[2], dv[3]);
        *(float4*)(dinv + base + 4) = make_float4(dv[4], dv[5], dv[6], dv[7]);
    } else {
        for (int j = 0; j < 8; j++) if (base + j < M) {
            off[base + j] = o[j]; cursor[base + j] = o[j]; dinv[base + j] = dv[j];
        }
    }
    if (bid == nb - 1 && t == 255) off[M] = sbase + btotal;
}

// 2 edges per thread, 16B index loads
__global__ __launch_bounds__(256) void fill_k(const void* __restrict__ ei, int E,
                                              const int* __restrict__ flags,
                                              int* __restrict__ cursor, int* __restrict__ eidx) {
    const int i2 = (blockIdx.x * 256 + threadIdx.x) * 2;
    if (i2 >= E) return;
    int s0, d0, s1 = -1, d1 = -1;
    bool two = (i2 + 1 < E);
    if (flags[1]) {
        const long long* sp = (const long long*)ei;
        const long long* dp = sp + E;
        if (two) {
            longlong2 sv = *(const longlong2*)(sp + i2);
            longlong2 dv = *(const longlong2*)(dp + i2);
            s0 = (int)sv.x; s1 = (int)sv.y; d0 = (int)dv.x; d1 = (int)dv.y;
        } else { s0 = (int)sp[i2]; d0 = (int)dp[i2]; }
    } else {
        const int* sp = (const int*)ei;
        const int* dp = sp + E;
        if (two) {
            int2 sv = *(const int2*)(sp + i2);
            int2 dv = *(const int2*)(dp + i2);
            s0 = sv.x; s1 = sv.y; d0 = dv.x; d1 = dv.y;
        } else { s0 = sp[i2]; d0 = dp[i2]; }
    }
    int p0 = atomicAdd(&cursor[d0], 1);
    eidx[p0] = s0;
    if (two) {
        int p1 = atomicAdd(&cursor[d1], 1);
        eidx[p1] = s1;
    }
}

// ===== MFMA GEMM v3: 64 rows/block (4 waves x 16 rows), 16KB LDS =====
template<int N>
__global__ __launch_bounds__(256) void gemm_mfma_k(
    const void* __restrict__ X, const uint4* __restrict__ wpk,
    const float* __restrict__ dinv, u16* __restrict__ HS,
    const int* __restrict__ flags, int x_is_ext, int M)
{
    constexpr int NT = N / 16;                  // n-tiles
    constexpr int NC8 = N / 8;                  // 16B chunks per output row
    __shared__ u32 xlds[64 * 64];               // 64 rows x 256B bf16 (16 KB)
    const int t = threadIdx.x;
    const int wave = t >> 6, lane = t & 63;
    const int q = lane >> 4, m = lane & 15;
    const bool xf32 = (x_is_ext != 0) && (flags[0] != 0);
    const int row0 = blockIdx.x * 64;

    // ---- stage X tile -> LDS (coalesced; 1024 chunks of 16B bf16) ----
    for (int c = t; c < 1024; c += 256) {
        const int row = c >> 4, c8 = c & 15;
        const int grow = row0 + row;
        uint4 pk = make_uint4(0u, 0u, 0u, 0u);
        if (grow < M) {
            if (xf32) {
                const float* xp = (const float*)X + (size_t)grow * 128 + c8 * 8;
                float4 u = *(const float4*)xp;
                float4 v = *(const float4*)(xp + 4);
                pk.x = packbf(u.x, u.y); pk.y = packbf(u.z, u.w);
                pk.z = packbf(v.x, v.y); pk.w = packbf(v.z, v.w);
            } else {
                pk = *(const uint4*)((const u16*)X + (size_t)grow * 128 + c8 * 8);
            }
        }
        *(uint4*)&xlds[row * 64 + c8 * 4] = pk;
    }
    __syncthreads();

    // ---- A-fragments from LDS (wave's own 16 rows) ----
    union { uint4 u; short8 v; } a[4];
    #pragma unroll
    for (int s = 0; s < 4; s++)
        a[s].u = *(const uint4*)&xlds[(wave * 16 + m) * 64 + (s * 4 + q) * 4];

    // ---- MFMA loop; B-frags direct from global wpk (L2-resident) ----
    f32x4 acc[NT];
    #pragma unroll
    for (int tt = 0; tt < NT; tt++)
        acc[tt] = (f32x4){0.f, 0.f, 0.f, 0.f};

    #pragma unroll
    for (int s = 0; s < 4; s++) {
        union { uint4 u; short8 v; } b[NT];
        #pragma unroll
        for (int tt = 0; tt < NT; tt++)
            b[tt].u = wpk[(s * 4 + q) * N + tt * 16 + m];
        #pragma unroll
        for (int tt = 0; tt < NT; tt++)
            acc[tt] = __builtin_amdgcn_mfma_f32_16x16x32_bf16(
                a[s].v, b[tt].v, acc[tt], 0, 0, 0);
    }

    // ---- epilogue: dinv scale, repack via wave-private LDS, 16B stores ----
    float dv[4];
    #pragma unroll
    for (int r = 0; r < 4; r++) {
        const int grow = row0 + wave * 16 + q * 4 + r;
        dv[r] = (grow < M) ? dinv[grow] : 0.f;
    }

    u16* orow = (u16*)&xlds[wave * 16 * 64];    // wave-private 4KB region
    #pragma unroll
    for (int tt = 0; tt < NT; tt++)
        #pragma unroll
        for (int r = 0; r < 4; r++)
            orow[(q * 4 + r) * N + tt * 16 + m] = f2bf(acc[tt][r] * dv[r]);

    constexpr int ITER = 16 * NC8 / 64;         // 4 (N=128) / 2 (N=64)
    #pragma unroll
    for (int j = 0; j < ITER; j++) {
        const int cc = lane + j * 64;
        const int lrow = cc / NC8, c8 = cc % NC8;
        const int grow = row0 + wave * 16 + lrow;
        uint4 v = *(const uint4*)&((const u32*)orow)[lrow * (N / 2) + c8 * 4];
        if (grow < M)
            *(uint4*)(HS + (size_t)grow * N + c8 * 8) = v;
    }
}

// out[i,:] = act( dinv[i] * (sum_{j in N(i)} hs[j,:] + hs[i,:]) + bias )
// TPN = N/8 lanes/node, 16B gathers, 4-edge unroll for MLP.
template<int N, bool RELU>
__global__ __launch_bounds__(256) void aggregate_k(
    const u16* __restrict__ hs, const int* __restrict__ eidx,
    const int* __restrict__ off, const float* __restrict__ dinv,
    const void* __restrict__ bias, void* __restrict__ out,
    const int* __restrict__ flags, int out_is_ext, int M)
{
    constexpr int TPN = N / 8;               // threads per node, 8 cols each
    constexpr int NPB = 256 / TPN;
    const int node = blockIdx.x * NPB + threadIdx.x / TPN;
    const int lane = threadIdx.x % TPN;
    if (node >= M) return;
    const int f32io = flags[0];
    const int beg = off[node], end = off[node + 1];
    const int c8 = lane * 8;
    const u16* __restrict__ hrow = hs + c8;

    float a[8];
    {
        uint4 sp = *(const uint4*)(hrow + (size_t)node * N);   // self-loop term
        const u16* s = (const u16*)&sp;
        #pragma unroll
        for (int j = 0; j < 8; j++) a[j] = bf2f(s[j]);
    }

    int p = beg;
    for (; p + 4 <= end; p += 4) {
        const int s0 = eidx[p + 0], s1 = eidx[p + 1];
        const int s2 = eidx[p + 2], s3 = eidx[p + 3];
        uint4 v0 = *(const uint4*)(hrow + (size_t)s0 * N);
        uint4 v1 = *(const uint4*)(hrow + (size_t)s1 * N);
        uint4 v2 = *(const uint4*)(hrow + (size_t)s2 * N);
        uint4 v3 = *(const uint4*)(hrow + (size_t)s3 * N);
        const u16* q0 = (const u16*)&v0; const u16* q1 = (const u16*)&v1;
        const u16* q2 = (const u16*)&v2; const u16* q3 = (const u16*)&v3;
        #pragma unroll
        for (int j = 0; j < 8; j++)
            a[j] += (bf2f(q0[j]) + bf2f(q1[j])) + (bf2f(q2[j]) + bf2f(q3[j]));
    }
    for (; p < end; p++) {
        const int s = eidx[p];
        uint4 v = *(const uint4*)(hrow + (size_t)s * N);
        const u16* q = (const u16*)&v;
        #pragma unroll
        for (int j = 0; j < 8; j++) a[j] += bf2f(q[j]);
    }

    const float dv = dinv[node];
    float b[8];
    if (f32io) {
        float4 u = *(const float4*)((const float*)bias + c8);
        float4 v = *(const float4*)((const float*)bias + c8 + 4);
        b[0] = u.x; b[1] = u.y; b[2] = u.z; b[3] = u.w;
        b[4] = v.x; b[5] = v.y; b[6] = v.z; b[7] = v.w;
    } else {
        uint4 u = *(const uint4*)((const u16*)bias + c8);
        const u16* s = (const u16*)&u;
        #pragma unroll
        for (int j = 0; j < 8; j++) b[j] = bf2f(s[j]);
    }
    float o[8];
    #pragma unroll
    for (int j = 0; j < 8; j++) {
        o[j] = fmaf(dv, a[j], b[j]);
        if (RELU) o[j] = fmaxf(o[j], 0.f);
    }
    if (out_is_ext && f32io) {
        float* op = (float*)out + (size_t)node * N + c8;
        *(float4*)op       = make_float4(o[0], o[1], o[2], o[3]);
        *(float4*)(op + 4) = make_float4(o[4], o[5], o[6], o[7]);
    } else {
        uint4 pk;
        pk.x = packbf(o[0], o[1]); pk.y = packbf(o[2], o[3]);
        pk.z = packbf(o[4], o[5]); pk.w = packbf(o[6], o[7]);
        *(uint4*)((u16*)out + (size_t)node * N + c8) = pk;
    }
}

extern "C" void kernel_launch(void* const* d_in, const int* in_sizes, int n_in,
                              void* d_out, int out_size, void* d_ws, size_t ws_size,
                              hipStream_t stream) {
    const void* x  = d_in[0];
    const void* ei = d_in[1];
    const void* W1 = d_in[2];
    const void* b1 = d_in[3];
    const void* W2 = d_in[4];
    const void* b2 = d_in[5];

    const int M = in_sizes[0] / 128;   // 100000 nodes
    const int E = in_sizes[1] / 2;     // 600000 edges
    const int NB = (M + SCAN_TILE - 1) / SCAN_TILE;   // 49 lookback blocks

    char* ws = (char*)d_ws;
    size_t offb = 0;
    auto alloc = [&](size_t bytes) -> void* {
        void* p = ws + offb; offb += (bytes + 255) & ~(size_t)255; return p;
    };
    int*   flags  = (int*)  alloc(256);
    u64*   lk     = (u64*)  alloc(2048);                  // lookback words (NB <= 256)
    uint4* wpk1   = (uint4*)alloc(16 * 128 * 16);         // 32 KB packed W1
    uint4* wpk2   = (uint4*)alloc(16 * 64 * 16);          // 16 KB packed W2
    int*   deg    = (int*)  alloc((size_t)M * 4);
    int*   off    = (int*)  alloc((size_t)(M + 1) * 4);
    int*   cursor = (int*)  alloc((size_t)M * 4);
    float* dinv   = (float*)alloc((size_t)M * 4);
    int*   eidx   = (int*)  alloc((size_t)E * 4);
    u16*   hs1    = (u16*)  alloc((size_t)M * 128 * 2);   // 25.6 MB
    u16*   out1   = (u16*)  alloc((size_t)M * 128 * 2);   // 25.6 MB (z = relu layer-1 out)
    u16*   hs2    = (u16*)  alloc((size_t)M * 64 * 2);    // 12.8 MB
    (void)ws_size; (void)n_in; (void)out_size;

    // 1: dtype detect + zero deg + zero lookback + wpack both weights
    prep_k<<<(M + 1023) / 1024, 256, 0, stream>>>((const u32*)x, (const u32*)ei, flags,
                                                  deg, M, W1, W2, wpk1, wpk2, lk, NB);
    // 2: degree count
    count_deg_k<<<(E + 511) / 512, 256, 0, stream>>>(ei, E, flags, deg);
    // 3: single-pass lookback scan -> off/cursor/dinv
    scan_lb_k<<<NB, 256, 0, stream>>>(deg, M, lk, off, cursor, dinv, NB);
    // 4: CSR fill
    fill_k<<<(E + 511) / 512, 256, 0, stream>>>(ei, E, flags, cursor, eidx);

    // 5: hs1 = (x @ W1) * dinv
    gemm_mfma_k<128><<<(M + 63) / 64, 256, 0, stream>>>(x, wpk1, dinv, hs1, flags, 1, M);
    // 6: z = relu(dinv*agg(hs1) + b1)
    aggregate_k<128, true><<<(M + 15) / 16, 256, 0, stream>>>(hs1, eidx, off, dinv, b1, out1,
                                                              flags, 0, M);
    // 7: hs2 = (z @ W2) * dinv
    gemm_mfma_k<64><<<(M + 63) / 64, 256, 0, stream>>>(out1, wpk2, dinv, hs2, flags, 0, M);
    // 8: out = dinv*agg(hs2) + b2
    aggregate_k<64, false><<<(M + 31) / 32, 256, 0, stream>>>(hs2, eidx, off, dinv, b2, d_out,
                                                              flags, 1, M);
}